// Round 1
// baseline (1048.043 us; speedup 1.0000x reference)
//
#include <hip/hip_runtime.h>
#include <math.h>

#define SZ1 4096
#define SZ2 4096
#define EMBD 32
#define KNN 20
#define HID 64

// ---------------------------------------------------------------------------
// Kernel 1: per (branch, index) top-20 nearest neighbors in embedding space.
// One 256-thread block per (branch, index). sim[] for all 4096 candidates in
// LDS, then 20 block-wide argmin passes (remove-and-rescan).
// ---------------------------------------------------------------------------
__global__ __launch_bounds__(256) void knn_kernel(
    const float* __restrict__ emb1, const float* __restrict__ emb2,
    int* __restrict__ nbr, float* __restrict__ wv)
{
    const int bid    = blockIdx.x;
    const int branch = bid >> 12;        // 0 -> emb1, 1 -> emb2
    const int i      = bid & 4095;
    const float* emb = branch ? emb2 : emb1;
    const int tid    = threadIdx.x;

    __shared__ float  sim[4096];         // 16 KB
    __shared__ float4 qs[8];
    __shared__ float  red_v[4];
    __shared__ int    red_i[4];

    if (tid < 8) qs[tid] = ((const float4*)(emb + (size_t)i * EMBD))[tid];
    __syncthreads();

    float4 q[8];
    float qq = 0.f;
#pragma unroll
    for (int d = 0; d < 8; ++d) {
        q[d] = qs[d];
        qq += q[d].x * q[d].x + q[d].y * q[d].y + q[d].z * q[d].z + q[d].w * q[d].w;
    }

    // distances: d2 = ||q||^2 + ||e||^2 - 2 q.e  (match reference formula)
    for (int j = tid; j < 4096; j += 256) {
        const float4* row = (const float4*)(emb + (size_t)j * EMBD);
        float dot = 0.f, ee = 0.f;
#pragma unroll
        for (int d = 0; d < 8; ++d) {
            float4 e = row[d];
            dot += e.x * q[d].x + e.y * q[d].y + e.z * q[d].z + e.w * q[d].w;
            ee  += e.x * e.x + e.y * e.y + e.z * e.z + e.w * e.w;
        }
        float d2 = qq + ee - 2.f * dot;
        float s  = sqrtf(fmaxf(d2, 0.f)) + 0.001f;
        sim[j] = (j == i) ? 1e30f : s;   // exclude self (ref: self forced to
                                         // rank-1 by sim=0, then sliced off)
    }
    __syncthreads();

    int*   nb_out = nbr + ((size_t)branch * SZ1 + i) * KNN;
    float* w_out  = wv  + ((size_t)branch * SZ1 + i) * KNN;

    for (int k = 0; k < KNN; ++k) {
        float best = 1e30f; int bi = -1;
        for (int j = tid; j < 4096; j += 256) {
            float v = sim[j];
            if (v < best) { best = v; bi = j; }
        }
#pragma unroll
        for (int off = 32; off; off >>= 1) {
            float ov = __shfl_down(best, off, 64);
            int   oi = __shfl_down(bi, off, 64);
            if (ov < best) { best = ov; bi = oi; }
        }
        if ((tid & 63) == 0) { red_v[tid >> 6] = best; red_i[tid >> 6] = bi; }
        __syncthreads();
        if (tid == 0) {
            float bv = red_v[0]; int bj = red_i[0];
#pragma unroll
            for (int w2 = 1; w2 < 4; ++w2)
                if (red_v[w2] < bv) { bv = red_v[w2]; bj = red_i[w2]; }
            nb_out[k] = bj;
            w_out[k]  = expf(-bv);       // TAU = 1
            sim[bj]   = 1e30f;           // remove winner
        }
        __syncthreads();
    }
}

// ---------------------------------------------------------------------------
// Kernel 2: per-sample gather + feature reduction + MLP.
// One 64-lane wave per sample (4 samples / 256-thread block).
// Half-wave 0 handles branch f1 (column gather), half-wave 1 handles f2
// (row gather). HID=64 hidden units = one per lane.
// ---------------------------------------------------------------------------
__global__ __launch_bounds__(256) void feat_mlp_kernel(
    const int* __restrict__ time, const int* __restrict__ idx1,
    const int* __restrict__ idx2,
    const float* __restrict__ residuals, const float* __restrict__ means,
    const float* __restrict__ stds,
    const int* __restrict__ nbr, const float* __restrict__ wv,
    const float* __restrict__ W1, const float* __restrict__ b1,
    const float* __restrict__ Wm, const float* __restrict__ bm,
    const float* __restrict__ Ws, const float* __restrict__ bs,
    float* __restrict__ out, int B)
{
    const int wave = threadIdx.x >> 6;
    const int lane = threadIdx.x & 63;
    const int s    = blockIdx.x * 4 + wave;
    if (s >= B) return;

    const int t  = time[s];
    const int i1 = idx1[s];
    const int i2 = idx2[s];
    const size_t base = (size_t)t * SZ1 * SZ2;

    const int half = lane >> 5;   // 0: f1 (emb1/index1), 1: f2 (emb2/index2)
    const int k    = lane & 31;

    float y = 0.f, w = 0.f;
    if (k < KNN) {
        if (half == 0) {
            const size_t o = ((size_t)0 * SZ1 + i1) * KNN + k;
            const int nb = nbr[o];
            y = residuals[base + (size_t)nb * SZ2 + i2];
            w = wv[o];
        } else {
            const size_t o = ((size_t)1 * SZ1 + i2) * KNN + k;
            const int nb = nbr[o];
            y = residuals[base + (size_t)i1 * SZ2 + nb];
            w = wv[o];
        }
    }

    // butterfly reductions within each 32-lane half
    float wy = w * y, sw = w, sy = y;
#pragma unroll
    for (int off = 16; off; off >>= 1) {
        wy += __shfl_xor(wy, off, 32);
        sw += __shfl_xor(sw, off, 32);
        sy += __shfl_xor(sy, off, 32);
    }
    const float m   = sy * (1.f / KNN);
    float dev = (k < KNN) ? (y - m) : 0.f;
    float ss  = dev * dev;
#pragma unroll
    for (int off = 16; off; off >>= 1) ss += __shfl_xor(ss, off, 32);

    const float wmean = wy / sw;
    const float sd    = sqrtf(ss * (1.f / (KNN - 1)));  // ddof=1

    // broadcast branch features to all 64 lanes
    const float f_wm1 = __shfl(wmean, 0, 64);
    const float f_sw1 = __shfl(sw,    0, 64);
    const float f_sd1 = __shfl(sd,    0, 64);
    const float f_wm2 = __shfl(wmean, 32, 64);
    const float f_sw2 = __shfl(sw,    32, 64);
    const float f_sd2 = __shfl(sd,    32, 64);

    const float mn  = means[base + (size_t)i1 * SZ2 + i2];
    const float sdv = stds [base + (size_t)i1 * SZ2 + i2];

    const float feats[8] = { f_wm1, f_sw1, f_sd1, f_wm2, f_sw2, f_sd2, mn, sdv };

    // hidden layer: one unit per lane (HID == 64 == wave size)
    const float* wrow = W1 + lane * 8;
    float h = b1[lane];
#pragma unroll
    for (int f = 0; f < 8; ++f) h += feats[f] * wrow[f];
    h = fmaxf(h, 0.f);

    float mo = h * Wm[lane];
    float so = h * Ws[lane];
#pragma unroll
    for (int off = 32; off; off >>= 1) {
        mo += __shfl_xor(mo, off, 64);
        so += __shfl_xor(so, off, 64);
    }
    if (lane == 0) {
        out[s]     = mo + bm[0];
        out[B + s] = so + bs[0];
    }
}

extern "C" void kernel_launch(void* const* d_in, const int* in_sizes, int n_in,
                              void* d_out, int out_size, void* d_ws, size_t ws_size,
                              hipStream_t stream)
{
    const int*   time      = (const int*)d_in[0];
    const int*   idx1      = (const int*)d_in[1];
    const int*   idx2      = (const int*)d_in[2];
    const float* residuals = (const float*)d_in[3];
    const float* means     = (const float*)d_in[4];
    const float* stds      = (const float*)d_in[5];
    const float* emb1      = (const float*)d_in[6];
    const float* emb2      = (const float*)d_in[7];
    const float* W1        = (const float*)d_in[8];
    const float* b1        = (const float*)d_in[9];
    const float* Wm        = (const float*)d_in[10];
    const float* bm        = (const float*)d_in[11];
    const float* Ws        = (const float*)d_in[12];
    const float* bs        = (const float*)d_in[13];
    float* out = (float*)d_out;

    const int B = in_sizes[0];

    // workspace: nbr [2][4096][20] int32, wv [2][4096][20] f32  (~1.3 MB)
    int*   nbr = (int*)d_ws;
    float* wv  = (float*)((char*)d_ws + (size_t)2 * SZ1 * KNN * sizeof(int));

    knn_kernel<<<2 * SZ1, 256, 0, stream>>>(emb1, emb2, nbr, wv);
    feat_mlp_kernel<<<(B + 3) / 4, 256, 0, stream>>>(
        time, idx1, idx2, residuals, means, stds, nbr, wv,
        W1, b1, Wm, bm, Ws, bs, out, B);
}